// Round 1
// baseline (659.236 us; speedup 1.0000x reference)
//
#include <hip/hip_runtime.h>
#include <math.h>

#define N_NODES 20000
#define N_EDGES 320000
#define DIM_IN 128
#define HID 64
#define HEADS 4
#define LAYERS 3
#define GRAPHS 128
#define QKVS 832   // 256 q | 256 k | 256 v | 64 s

// ---------------- CSR build ----------------

__global__ void zero_kernel(int* __restrict__ p, int n) {
    int i = blockIdx.x * 256 + threadIdx.x;
    if (i < n) p[i] = 0;
}

__global__ void hist_kernel(const int* __restrict__ dst, int* __restrict__ counts, int n) {
    int e = blockIdx.x * 256 + threadIdx.x;
    if (e < n) atomicAdd(&counts[dst[e]], 1);
}

__global__ __launch_bounds__(1024) void scan_kernel(const int* __restrict__ counts,
                                                    int* __restrict__ offs,
                                                    int* __restrict__ cursor, int n) {
    __shared__ int lds[1024];
    int tid = threadIdx.x;
    int base = 0;
    int nchunks = (n + 1023) / 1024;
    for (int chunk = 0; chunk < nchunks; ++chunk) {
        int i = chunk * 1024 + tid;
        int v = (i < n) ? counts[i] : 0;
        lds[tid] = v;
        __syncthreads();
        for (int off = 1; off < 1024; off <<= 1) {
            int t = (tid >= off) ? lds[tid - off] : 0;
            __syncthreads();
            lds[tid] += t;
            __syncthreads();
        }
        int incl = lds[tid];
        int excl = incl - v;
        if (i < n) { offs[i] = base + excl; cursor[i] = base + excl; }
        int total = lds[1023];
        __syncthreads();
        base += total;
    }
    if (tid == 0) offs[n] = base;
}

__global__ void scatter_kernel(const int* __restrict__ src, const int* __restrict__ dst,
                               int* __restrict__ cursor, int* __restrict__ csr, int n) {
    int e = blockIdx.x * 256 + threadIdx.x;
    if (e < n) {
        int d = dst[e];
        int pos = atomicAdd(&cursor[d], 1);
        csr[pos] = src[e];
    }
}

// ---------------- input linear: h0 = x @ linW + linb ----------------

__global__ __launch_bounds__(256) void lin_kernel(const float* __restrict__ x,
                                                  const float* __restrict__ W,
                                                  const float* __restrict__ b,
                                                  float* __restrict__ h0) {
    __shared__ float xt[32][DIM_IN];
    int tx = threadIdx.x;
    int row0 = blockIdx.x * 32;
    for (int idx = tx; idx < 32 * DIM_IN; idx += 256) {
        int r = idx / DIM_IN, c = idx % DIM_IN;
        xt[r][c] = x[(size_t)(row0 + r) * DIM_IN + c];
    }
    __syncthreads();
    int col = tx & 63;
    int sub = tx >> 6;
    float acc[8];
#pragma unroll
    for (int r = 0; r < 8; ++r) acc[r] = 0.f;
    for (int k = 0; k < DIM_IN; ++k) {
        float w = W[k * HID + col];
#pragma unroll
        for (int r = 0; r < 8; ++r) acc[r] += xt[r * 4 + sub][k] * w;
    }
    float bias = b[col];
#pragma unroll
    for (int r = 0; r < 8; ++r) {
        int row = row0 + r * 4 + sub;
        h0[(size_t)row * HID + col] = acc[r] + bias;
    }
}

// ---------------- per-layer projection: qkv[N,832] = h @ [Wq|Wk|Wv|Ws] + b ----------------

__global__ __launch_bounds__(256) void proj_kernel(const float* __restrict__ h,
                                                   const float* __restrict__ Wq, const float* __restrict__ bq,
                                                   const float* __restrict__ Wk, const float* __restrict__ bk,
                                                   const float* __restrict__ Wv, const float* __restrict__ bv,
                                                   const float* __restrict__ Ws, const float* __restrict__ bs,
                                                   float* __restrict__ qkv) {
    __shared__ float ht[16][HID];
    int tx = threadIdx.x;
    int row0 = blockIdx.x * 16;
    for (int idx = tx; idx < 16 * HID; idx += 256) {
        ht[idx >> 6][idx & 63] = h[(size_t)(row0 + (idx >> 6)) * HID + (idx & 63)];
    }
    __syncthreads();
    int j = blockIdx.y * 256 + tx;
    if (j >= QKVS) return;
    const float* W; int ld; float bias;
    if (j < 256)      { W = Wq + j;         ld = 256; bias = bq[j]; }
    else if (j < 512) { W = Wk + (j - 256); ld = 256; bias = bk[j - 256]; }
    else if (j < 768) { W = Wv + (j - 512); ld = 256; bias = bv[j - 512]; }
    else              { W = Ws + (j - 768); ld = 64;  bias = bs[j - 768]; }
    float acc[16];
#pragma unroll
    for (int r = 0; r < 16; ++r) acc[r] = 0.f;
    for (int k = 0; k < HID; ++k) {
        float w = W[(size_t)k * ld];
#pragma unroll
        for (int r = 0; r < 16; ++r) acc[r] += ht[r][k] * w;
    }
#pragma unroll
    for (int r = 0; r < 16; ++r) {
        qkv[(size_t)(row0 + r) * QKVS + j] = acc[r] + bias;
    }
}

// ---------------- per-node edge attention (one wave per node) ----------------
// lane = h*16 + c16; each lane owns channels [c16*4, c16*4+4) of head h.

__global__ __launch_bounds__(256) void edge_kernel(const float* __restrict__ qkv,
                                                   const int* __restrict__ offs,
                                                   const int* __restrict__ csr,
                                                   float* __restrict__ hout) {
    int wave = threadIdx.x >> 6;
    int lane = threadIdx.x & 63;
    int node = blockIdx.x * 4 + wave;
    if (node >= N_NODES) return;
    int hh = lane >> 4;
    int cb = (lane & 15) * 4;

    const float* nb = qkv + (size_t)node * QKVS;
    float4 q = *(const float4*)(nb + hh * 64 + cb);

    float m = -INFINITY, l = 0.f;
    float4 acc = make_float4(0.f, 0.f, 0.f, 0.f);

    int e0 = offs[node], e1 = offs[node + 1];
    for (int e = e0; e < e1; ++e) {
        int j = csr[e];
        const float* kb = qkv + (size_t)j * QKVS;
        float4 kv = *(const float4*)(kb + 256 + hh * 64 + cb);
        float4 vv = *(const float4*)(kb + 512 + hh * 64 + cb);
        float p = q.x * kv.x + q.y * kv.y + q.z * kv.z + q.w * kv.w;
        p += __shfl_xor(p, 1);
        p += __shfl_xor(p, 2);
        p += __shfl_xor(p, 4);
        p += __shfl_xor(p, 8);
        float alpha = p * 0.125f;   // 1/sqrt(64)
        float nm = fmaxf(m, alpha);
        float sc = __expf(m - nm);
        float pe = __expf(alpha - nm);
        l = l * sc + pe;
        acc.x = acc.x * sc + pe * vv.x;
        acc.y = acc.y * sc + pe * vv.y;
        acc.z = acc.z * sc + pe * vv.z;
        acc.w = acc.w * sc + pe * vv.w;
        m = nm;
    }

    float inv = (l > 0.f) ? (1.f / l) : 0.f;
    float4 r;
    r.x = acc.x * inv;
    r.y = acc.y * inv;
    r.z = acc.z * inv;
    r.w = acc.w * inv;
    // sum across the 4 head groups (lanes differing in bits 4,5)
    r.x += __shfl_xor(r.x, 16); r.x += __shfl_xor(r.x, 32);
    r.y += __shfl_xor(r.y, 16); r.y += __shfl_xor(r.y, 32);
    r.z += __shfl_xor(r.z, 16); r.z += __shfl_xor(r.z, 32);
    r.w += __shfl_xor(r.w, 16); r.w += __shfl_xor(r.w, 32);

    if (hh == 0) {
        float4 s = *(const float4*)(nb + 768 + cb);
        float4 o;
        o.x = fmaxf(r.x * 0.25f + s.x, 0.f);
        o.y = fmaxf(r.y * 0.25f + s.y, 0.f);
        o.z = fmaxf(r.z * 0.25f + s.z, 0.f);
        o.w = fmaxf(r.w * 0.25f + s.w, 0.f);
        *(float4*)(hout + (size_t)node * HID + cb) = o;
    }
}

// ---------------- global add pool ----------------

__global__ __launch_bounds__(256) void pool_kernel(const float* __restrict__ h,
                                                   const int* __restrict__ batch,
                                                   float* __restrict__ out) {
    int g = blockIdx.x;
    int lo = 0, hi = N_NODES;
    while (lo < hi) { int mid = (lo + hi) >> 1; if (batch[mid] < g) lo = mid + 1; else hi = mid; }
    int start = lo;
    hi = N_NODES;
    while (lo < hi) { int mid = (lo + hi) >> 1; if (batch[mid] < g + 1) lo = mid + 1; else hi = mid; }
    int end = lo;
    int c = threadIdx.x & 63;
    int sub = threadIdx.x >> 6;
    float acc = 0.f;
    for (int i = start + sub; i < end; i += 4) acc += h[(size_t)i * HID + c];
    __shared__ float lds[4][64];
    lds[sub][c] = acc;
    __syncthreads();
    if (sub == 0) out[g * HID + c] = lds[0][c] + lds[1][c] + lds[2][c] + lds[3][c];
}

// ---------------- launch ----------------

extern "C" void kernel_launch(void* const* d_in, const int* in_sizes, int n_in,
                              void* d_out, int out_size, void* d_ws, size_t ws_size,
                              hipStream_t stream) {
    const float* x    = (const float*)d_in[0];
    const int*   edge = (const int*)d_in[1];
    const int*   batch= (const int*)d_in[2];
    const float* linW = (const float*)d_in[3];
    const float* linb = (const float*)d_in[4];
    const float* Wq   = (const float*)d_in[5];
    const float* bq   = (const float*)d_in[6];
    const float* Wk   = (const float*)d_in[7];
    const float* bk   = (const float*)d_in[8];
    const float* Wv   = (const float*)d_in[9];
    const float* bv   = (const float*)d_in[10];
    const float* Ws   = (const float*)d_in[11];
    const float* bs   = (const float*)d_in[12];
    float* out = (float*)d_out;

    const int* src = edge;
    const int* dst = edge + N_EDGES;

    float* h0  = (float*)d_ws;
    float* h1  = h0 + (size_t)N_NODES * HID;
    float* qkv = h1 + (size_t)N_NODES * HID;
    int* counts = (int*)(qkv + (size_t)N_NODES * QKVS);
    int* offs   = counts + N_NODES;
    int* cursor = offs + N_NODES + 1;
    int* csr    = cursor + N_NODES;

    // CSR build (dst is fixed across layers)
    zero_kernel<<<(N_NODES + 255) / 256, 256, 0, stream>>>(counts, N_NODES);
    hist_kernel<<<(N_EDGES + 255) / 256, 256, 0, stream>>>(dst, counts, N_EDGES);
    scan_kernel<<<1, 1024, 0, stream>>>(counts, offs, cursor, N_NODES);
    scatter_kernel<<<(N_EDGES + 255) / 256, 256, 0, stream>>>(src, dst, cursor, csr, N_EDGES);

    // input linear
    lin_kernel<<<N_NODES / 32, 256, 0, stream>>>(x, linW, linb, h0);

    float* hc = h0;
    float* hn = h1;
    for (int l = 0; l < LAYERS; ++l) {
        dim3 pg(N_NODES / 16, 4);
        proj_kernel<<<pg, 256, 0, stream>>>(hc,
            Wq + (size_t)l * HID * 256, bq + (size_t)l * 256,
            Wk + (size_t)l * HID * 256, bk + (size_t)l * 256,
            Wv + (size_t)l * HID * 256, bv + (size_t)l * 256,
            Ws + (size_t)l * HID * 64,  bs + (size_t)l * 64,
            qkv);
        edge_kernel<<<N_NODES / 4, 256, 0, stream>>>(qkv, offs, csr, hn);
        float* t = hc; hc = hn; hn = t;
    }

    pool_kernel<<<GRAPHS, 256, 0, stream>>>(hc, batch, out);
}

// Round 2
// 486.406 us; speedup vs baseline: 1.3553x; 1.3553x over previous
//
#include <hip/hip_runtime.h>
#include <math.h>

#define N_NODES 20000
#define N_EDGES 320000
#define DIM_IN 128
#define HID 64
#define HEADS 4
#define LAYERS 3
#define GRAPHS 128
#define QKVS 832   // logical cols: 256 q | 256 k | 256 v | 64 s
#define QSS 320    // stored f32 cols: 256 q | 64 s

typedef unsigned short ushort;
typedef ushort ushort8 __attribute__((ext_vector_type(8)));

__device__ __forceinline__ float bf2f(ushort u) {
    return __uint_as_float(((unsigned int)u) << 16);
}
__device__ __forceinline__ ushort f2bf(float f) {
    unsigned int b = __float_as_uint(f);
    return (ushort)((b + 0x7FFFu + ((b >> 16) & 1u)) >> 16);
}

// ---------------- CSR build ----------------

__global__ void zero_kernel(int* __restrict__ p, int n) {
    int i = blockIdx.x * 256 + threadIdx.x;
    if (i < n) p[i] = 0;
}

__global__ void hist_kernel(const int* __restrict__ dst, int* __restrict__ counts, int n) {
    int e = blockIdx.x * 256 + threadIdx.x;
    if (e < n) atomicAdd(&counts[dst[e]], 1);
}

__global__ __launch_bounds__(1024) void scan_kernel(const int* __restrict__ counts,
                                                    int* __restrict__ offs,
                                                    int* __restrict__ cursor, int n) {
    __shared__ int wsum[16];
    __shared__ int wpre[17];
    int tid = threadIdx.x;
    int wave = tid >> 6, lane = tid & 63;
    int base = 0;
    int nchunks = (n + 1023) / 1024;
    for (int chunk = 0; chunk < nchunks; ++chunk) {
        int i = chunk * 1024 + tid;
        int v = (i < n) ? counts[i] : 0;
        int s = v;
#pragma unroll
        for (int off = 1; off < 64; off <<= 1) {
            int t = __shfl_up(s, off);
            if (lane >= off) s += t;
        }
        if (lane == 63) wsum[wave] = s;
        __syncthreads();
        if (tid < 16) {
            int w = wsum[tid];
            int ws = w;
#pragma unroll
            for (int off = 1; off < 16; off <<= 1) {
                int t = __shfl_up(ws, off);
                if (lane >= off) ws += t;
            }
            wpre[tid] = ws - w;
            if (tid == 15) wpre[16] = ws;
        }
        __syncthreads();
        int excl = base + (s - v) + wpre[wave];
        if (i < n) { offs[i] = excl; cursor[i] = excl; }
        base += wpre[16];
        __syncthreads();
    }
    if (tid == 0) offs[n] = base;
}

__global__ void scatter_kernel(const int* __restrict__ src, const int* __restrict__ dst,
                               int* __restrict__ cursor, int* __restrict__ csr, int n) {
    int e = blockIdx.x * 256 + threadIdx.x;
    if (e < n) {
        int d = dst[e];
        int pos = atomicAdd(&cursor[d], 1);
        csr[pos] = src[e];
    }
}

// ---------------- input linear: h0 = x @ linW + linb ----------------

__global__ __launch_bounds__(256) void lin_kernel(const float* __restrict__ x,
                                                  const float* __restrict__ W,
                                                  const float* __restrict__ b,
                                                  float* __restrict__ h0) {
    __shared__ float xt[32][DIM_IN];
    int tx = threadIdx.x;
    int row0 = blockIdx.x * 32;
    for (int idx = tx; idx < 32 * DIM_IN; idx += 256) {
        int r = idx / DIM_IN, c = idx % DIM_IN;
        xt[r][c] = x[(size_t)(row0 + r) * DIM_IN + c];
    }
    __syncthreads();
    int col = tx & 63;
    int sub = tx >> 6;
    float acc[8];
#pragma unroll
    for (int r = 0; r < 8; ++r) acc[r] = 0.f;
    for (int k = 0; k < DIM_IN; k += 4) {
        float w0 = W[k * HID + col];
        float w1 = W[(k + 1) * HID + col];
        float w2 = W[(k + 2) * HID + col];
        float w3 = W[(k + 3) * HID + col];
#pragma unroll
        for (int r = 0; r < 8; ++r) {
            const float4 hv = *(const float4*)&xt[r * 4 + sub][k];
            acc[r] += hv.x * w0 + hv.y * w1 + hv.z * w2 + hv.w * w3;
        }
    }
    float bias = b[col];
#pragma unroll
    for (int r = 0; r < 8; ++r) {
        int row = row0 + r * 4 + sub;
        h0[(size_t)row * HID + col] = acc[r] + bias;
    }
}

// ---------------- per-layer projection ----------------
// writes qs[N][320] f32 (q|s) and kvpack[N][512] ushort (bf16 k|v interleaved:
// ushort index = (hh*16 + c16)*8 + isv*4 + (c&3))

__global__ __launch_bounds__(256) void proj_kernel(const float* __restrict__ h,
                                                   const float* __restrict__ Wq, const float* __restrict__ bq,
                                                   const float* __restrict__ Wk, const float* __restrict__ bk,
                                                   const float* __restrict__ Wv, const float* __restrict__ bv,
                                                   const float* __restrict__ Ws, const float* __restrict__ bs,
                                                   float* __restrict__ qs,
                                                   ushort* __restrict__ kvpack) {
    __shared__ float ht[16][HID];
    int tx = threadIdx.x;
    int row0 = blockIdx.x * 16;
    for (int idx = tx; idx < 16 * HID; idx += 256) {
        ht[idx >> 6][idx & 63] = h[(size_t)(row0 + (idx >> 6)) * HID + (idx & 63)];
    }
    __syncthreads();
    int j = blockIdx.y * 256 + tx;
    if (j >= QKVS) return;
    const float* W; int ld; float bias;
    if (j < 256)      { W = Wq + j;         ld = 256; bias = bq[j]; }
    else if (j < 512) { W = Wk + (j - 256); ld = 256; bias = bk[j - 256]; }
    else if (j < 768) { W = Wv + (j - 512); ld = 256; bias = bv[j - 512]; }
    else              { W = Ws + (j - 768); ld = 64;  bias = bs[j - 768]; }
    float acc[16];
#pragma unroll
    for (int r = 0; r < 16; ++r) acc[r] = 0.f;
    for (int k = 0; k < HID; k += 4) {
        float w0 = W[(size_t)k * ld];
        float w1 = W[(size_t)(k + 1) * ld];
        float w2 = W[(size_t)(k + 2) * ld];
        float w3 = W[(size_t)(k + 3) * ld];
#pragma unroll
        for (int r = 0; r < 16; ++r) {
            const float4 hv = *(const float4*)&ht[r][k];
            acc[r] += hv.x * w0 + hv.y * w1 + hv.z * w2 + hv.w * w3;
        }
    }
    if (j < 256) {
#pragma unroll
        for (int r = 0; r < 16; ++r)
            qs[(size_t)(row0 + r) * QSS + j] = acc[r] + bias;
    } else if (j < 768) {
        int ck = j - 256;            // 0..511
        int isv = ck >> 8;           // 0 = k, 1 = v
        int ch = ck & 255;           // hh*64 + c
        int hh = ch >> 6, c = ch & 63;
        int pos = ((hh * 16 + (c >> 2)) * 8) + isv * 4 + (c & 3);
#pragma unroll
        for (int r = 0; r < 16; ++r)
            kvpack[(size_t)(row0 + r) * 512 + pos] = f2bf(acc[r] + bias);
    } else {
#pragma unroll
        for (int r = 0; r < 16; ++r)
            qs[(size_t)(row0 + r) * QSS + 256 + (j - 768)] = acc[r] + bias;
    }
}

// ---------------- per-node edge attention (one wave per node) ----------------
// lane = hh*16 + c16; lane's 16B kvpack load holds its k4 (bf16) and v4 (bf16).

__global__ __launch_bounds__(256) void edge_kernel(const float* __restrict__ qs,
                                                   const ushort8* __restrict__ kvp,
                                                   const int* __restrict__ offs,
                                                   const int* __restrict__ csr,
                                                   float* __restrict__ hout) {
    int wave = threadIdx.x >> 6;
    int lane = threadIdx.x & 63;
    int node = blockIdx.x * 4 + wave;
    if (node >= N_NODES) return;
    int hh = lane >> 4;
    int cb = (lane & 15) * 4;

    const float* nb = qs + (size_t)node * QSS;
    float4 q = *(const float4*)(nb + hh * 64 + cb);

    float m = -INFINITY, l = 0.f;
    float4 acc = make_float4(0.f, 0.f, 0.f, 0.f);

    int e0 = offs[node], e1 = offs[node + 1];
    int cnt = e1 - e0;

    ushort8 cur = (ushort8)(0);
    ushort8 nxt = (ushort8)(0);
    if (cnt > 0) cur = kvp[(size_t)csr[e0] * 64 + lane];
    if (cnt > 1) nxt = kvp[(size_t)csr[e0 + 1] * 64 + lane];

    for (int i = 0; i < cnt; ++i) {
        ushort8 u = cur;
        cur = nxt;
        if (i + 2 < cnt) nxt = kvp[(size_t)csr[e0 + i + 2] * 64 + lane];

        float p = q.x * bf2f(u[0]) + q.y * bf2f(u[1]) + q.z * bf2f(u[2]) + q.w * bf2f(u[3]);
        p += __shfl_xor(p, 1);
        p += __shfl_xor(p, 2);
        p += __shfl_xor(p, 4);
        p += __shfl_xor(p, 8);
        float alpha = p * 0.125f;   // 1/sqrt(64)
        float nm = fmaxf(m, alpha);
        float sc = __expf(m - nm);
        float pe = __expf(alpha - nm);
        l = l * sc + pe;
        acc.x = acc.x * sc + pe * bf2f(u[4]);
        acc.y = acc.y * sc + pe * bf2f(u[5]);
        acc.z = acc.z * sc + pe * bf2f(u[6]);
        acc.w = acc.w * sc + pe * bf2f(u[7]);
        m = nm;
    }

    float inv = (l > 0.f) ? (1.f / l) : 0.f;
    float4 r;
    r.x = acc.x * inv;
    r.y = acc.y * inv;
    r.z = acc.z * inv;
    r.w = acc.w * inv;
    r.x += __shfl_xor(r.x, 16); r.x += __shfl_xor(r.x, 32);
    r.y += __shfl_xor(r.y, 16); r.y += __shfl_xor(r.y, 32);
    r.z += __shfl_xor(r.z, 16); r.z += __shfl_xor(r.z, 32);
    r.w += __shfl_xor(r.w, 16); r.w += __shfl_xor(r.w, 32);

    if (hh == 0) {
        float4 s = *(const float4*)(nb + 256 + cb);
        float4 o;
        o.x = fmaxf(r.x * 0.25f + s.x, 0.f);
        o.y = fmaxf(r.y * 0.25f + s.y, 0.f);
        o.z = fmaxf(r.z * 0.25f + s.z, 0.f);
        o.w = fmaxf(r.w * 0.25f + s.w, 0.f);
        *(float4*)(hout + (size_t)node * HID + cb) = o;
    }
}

// ---------------- global add pool ----------------

__global__ __launch_bounds__(256) void pool_kernel(const float* __restrict__ h,
                                                   const int* __restrict__ batch,
                                                   float* __restrict__ out) {
    int g = blockIdx.x;
    int lo = 0, hi = N_NODES;
    while (lo < hi) { int mid = (lo + hi) >> 1; if (batch[mid] < g) lo = mid + 1; else hi = mid; }
    int start = lo;
    hi = N_NODES;
    while (lo < hi) { int mid = (lo + hi) >> 1; if (batch[mid] < g + 1) lo = mid + 1; else hi = mid; }
    int end = lo;
    int c = threadIdx.x & 63;
    int sub = threadIdx.x >> 6;
    float acc = 0.f;
    for (int i = start + sub; i < end; i += 4) acc += h[(size_t)i * HID + c];
    __shared__ float lds[4][64];
    lds[sub][c] = acc;
    __syncthreads();
    if (sub == 0) out[g * HID + c] = lds[0][c] + lds[1][c] + lds[2][c] + lds[3][c];
}

// ---------------- launch ----------------

extern "C" void kernel_launch(void* const* d_in, const int* in_sizes, int n_in,
                              void* d_out, int out_size, void* d_ws, size_t ws_size,
                              hipStream_t stream) {
    const float* x    = (const float*)d_in[0];
    const int*   edge = (const int*)d_in[1];
    const int*   batch= (const int*)d_in[2];
    const float* linW = (const float*)d_in[3];
    const float* linb = (const float*)d_in[4];
    const float* Wq   = (const float*)d_in[5];
    const float* bq   = (const float*)d_in[6];
    const float* Wk   = (const float*)d_in[7];
    const float* bk   = (const float*)d_in[8];
    const float* Wv   = (const float*)d_in[9];
    const float* bv   = (const float*)d_in[10];
    const float* Ws   = (const float*)d_in[11];
    const float* bs   = (const float*)d_in[12];
    float* out = (float*)d_out;

    const int* src = edge;
    const int* dst = edge + N_EDGES;

    float* h0  = (float*)d_ws;                                   // N*64
    float* h1  = h0 + (size_t)N_NODES * HID;                     // N*64
    float* qs  = h1 + (size_t)N_NODES * HID;                     // N*320
    ushort* kvpack = (ushort*)(qs + (size_t)N_NODES * QSS);      // N*512 ushort
    int* counts = (int*)(kvpack + (size_t)N_NODES * 512);
    int* offs   = counts + N_NODES;
    int* cursor = offs + N_NODES + 1;
    int* csr    = cursor + N_NODES;

    // CSR build (dst is fixed across layers)
    zero_kernel<<<(N_NODES + 255) / 256, 256, 0, stream>>>(counts, N_NODES);
    hist_kernel<<<(N_EDGES + 255) / 256, 256, 0, stream>>>(dst, counts, N_EDGES);
    scan_kernel<<<1, 1024, 0, stream>>>(counts, offs, cursor, N_NODES);
    scatter_kernel<<<(N_EDGES + 255) / 256, 256, 0, stream>>>(src, dst, cursor, csr, N_EDGES);

    // input linear
    lin_kernel<<<N_NODES / 32, 256, 0, stream>>>(x, linW, linb, h0);

    float* hc = h0;
    float* hn = h1;
    for (int l = 0; l < LAYERS; ++l) {
        dim3 pg(N_NODES / 16, 4);
        proj_kernel<<<pg, 256, 0, stream>>>(hc,
            Wq + (size_t)l * HID * 256, bq + (size_t)l * 256,
            Wk + (size_t)l * HID * 256, bk + (size_t)l * 256,
            Wv + (size_t)l * HID * 256, bv + (size_t)l * 256,
            Ws + (size_t)l * HID * 64,  bs + (size_t)l * 64,
            qs, kvpack);
        edge_kernel<<<N_NODES / 4, 256, 0, stream>>>(qs, (const ushort8*)kvpack, offs, csr, hn);
        float* t = hc; hc = hn; hn = t;
    }

    pool_kernel<<<GRAPHS, 256, 0, stream>>>(hc, batch, out);
}

// Round 3
// 445.886 us; speedup vs baseline: 1.4785x; 1.0909x over previous
//
#include <hip/hip_runtime.h>
#include <math.h>

#define N_NODES 20000
#define N_EDGES 320000
#define DIM_IN 128
#define HID 64
#define HEADS 4
#define LAYERS 3
#define GRAPHS 128
#define QSS 320    // stored f32 cols: 256 q | 64 s

typedef unsigned short ushort;
typedef ushort ushort8 __attribute__((ext_vector_type(8)));

__device__ __forceinline__ float bf2f(ushort u) {
    return __uint_as_float(((unsigned int)u) << 16);
}
__device__ __forceinline__ ushort f2bf(float f) {
    unsigned int b = __float_as_uint(f);
    return (ushort)((b + 0x7FFFu + ((b >> 16) & 1u)) >> 16);
}

// ---------------- CSR build ----------------

__global__ void hist_kernel(const int* __restrict__ dst, int* __restrict__ counts, int n) {
    int e = blockIdx.x * 256 + threadIdx.x;
    if (e < n) atomicAdd(&counts[dst[e]], 1);
}

// per-256-chunk sums
__global__ __launch_bounds__(256) void blocksum_kernel(const int* __restrict__ counts,
                                                       int* __restrict__ bsum, int n) {
    int i = blockIdx.x * 256 + threadIdx.x;
    int v = (i < n) ? counts[i] : 0;
    int lane = threadIdx.x & 63, wave = threadIdx.x >> 6;
#pragma unroll
    for (int off = 32; off >= 1; off >>= 1) v += __shfl_xor(v, off);
    __shared__ int ws[4];
    if (lane == 0) ws[wave] = v;
    __syncthreads();
    if (threadIdx.x == 0) bsum[blockIdx.x] = ws[0] + ws[1] + ws[2] + ws[3];
}

// single-block exclusive scan of the (<=128) chunk sums
__global__ __launch_bounds__(128) void scanb_kernel(const int* __restrict__ bsum,
                                                    int* __restrict__ bexcl, int nb) {
    int tid = threadIdx.x;
    int v = (tid < nb) ? bsum[tid] : 0;
    int lane = tid & 63, wave = tid >> 6;
    int s = v;
#pragma unroll
    for (int off = 1; off < 64; off <<= 1) {
        int t = __shfl_up(s, off);
        if (lane >= off) s += t;
    }
    __shared__ int w0sum;
    if (tid == 63) w0sum = s;
    __syncthreads();
    int excl = s - v + (wave ? w0sum : 0);
    if (tid < nb) bexcl[tid] = excl;
}

// per-chunk prefix + chunk base -> offs, cursor
__global__ __launch_bounds__(256) void expand_kernel(const int* __restrict__ counts,
                                                     const int* __restrict__ bexcl,
                                                     int* __restrict__ offs,
                                                     int* __restrict__ cursor, int n) {
    int i = blockIdx.x * 256 + threadIdx.x;
    int v = (i < n) ? counts[i] : 0;
    int lane = threadIdx.x & 63, wave = threadIdx.x >> 6;
    int s = v;
#pragma unroll
    for (int off = 1; off < 64; off <<= 1) {
        int t = __shfl_up(s, off);
        if (lane >= off) s += t;
    }
    __shared__ int wsum[4];
    if (lane == 63) wsum[wave] = s;
    __syncthreads();
    int add = bexcl[blockIdx.x];
    for (int w = 0; w < wave; ++w) add += wsum[w];
    int excl = add + s - v;
    if (i < n) { offs[i] = excl; cursor[i] = excl; }
    if (i == 0) offs[n] = N_EDGES;
}

__global__ void scatter_kernel(const int* __restrict__ src, const int* __restrict__ dst,
                               int* __restrict__ cursor, int* __restrict__ csr, int n) {
    int e = blockIdx.x * 256 + threadIdx.x;
    if (e < n) {
        int d = dst[e];
        int pos = atomicAdd(&cursor[d], 1);
        csr[pos] = src[e];
    }
}

// ---------------- input linear: h0 = x @ linW + linb ----------------

__global__ __launch_bounds__(256) void lin_kernel(const float* __restrict__ x,
                                                  const float* __restrict__ W,
                                                  const float* __restrict__ b,
                                                  float* __restrict__ h0) {
    __shared__ float xt[32][DIM_IN];
    int tx = threadIdx.x;
    int row0 = blockIdx.x * 32;
    for (int idx = tx; idx < 32 * DIM_IN; idx += 256) {
        int r = idx / DIM_IN, c = idx % DIM_IN;
        xt[r][c] = x[(size_t)(row0 + r) * DIM_IN + c];
    }
    __syncthreads();
    int col = tx & 63;
    int sub = tx >> 6;
    float acc[8];
#pragma unroll
    for (int r = 0; r < 8; ++r) acc[r] = 0.f;
    for (int k = 0; k < DIM_IN; k += 4) {
        float w0 = W[k * HID + col];
        float w1 = W[(k + 1) * HID + col];
        float w2 = W[(k + 2) * HID + col];
        float w3 = W[(k + 3) * HID + col];
#pragma unroll
        for (int r = 0; r < 8; ++r) {
            const float4 hv = *(const float4*)&xt[r * 4 + sub][k];
            acc[r] += hv.x * w0 + hv.y * w1 + hv.z * w2 + hv.w * w3;
        }
    }
    float bias = b[col];
#pragma unroll
    for (int r = 0; r < 8; ++r) {
        int row = row0 + r * 4 + sub;
        h0[(size_t)row * HID + col] = acc[r] + bias;
    }
}

// ---------------- per-layer projection ----------------
// Each thread owns q-col tx, k-col tx, v-col tx; wave 0 additionally s-col tx.
// Writes qs[N][320] f32 (q|s) and kvpack[N][512] ushort bf16
// (ushort index = (hh*16 + c16)*8 + isv*4 + (c&3)).

__global__ __launch_bounds__(256) void proj_kernel(const float* __restrict__ h,
                                                   const float* __restrict__ Wq, const float* __restrict__ bq,
                                                   const float* __restrict__ Wk, const float* __restrict__ bk,
                                                   const float* __restrict__ Wv, const float* __restrict__ bv,
                                                   const float* __restrict__ Ws, const float* __restrict__ bs,
                                                   float* __restrict__ qs,
                                                   ushort* __restrict__ kvpack) {
    __shared__ float ht[16][HID];
    int tx = threadIdx.x;
    int row0 = blockIdx.x * 16;
    for (int idx = tx; idx < 16 * HID; idx += 256) {
        ht[idx >> 6][idx & 63] = h[(size_t)(row0 + (idx >> 6)) * HID + (idx & 63)];
    }
    __syncthreads();
    const bool do_s = (tx < 64);   // wave-uniform (wave 0 only)
    float accq[16], acck[16], accv[16], accs[16];
#pragma unroll
    for (int r = 0; r < 16; ++r) { accq[r] = 0.f; acck[r] = 0.f; accv[r] = 0.f; accs[r] = 0.f; }

    for (int k = 0; k < HID; k += 4) {
        float wq0 = Wq[(size_t)k * 256 + tx];
        float wq1 = Wq[(size_t)(k + 1) * 256 + tx];
        float wq2 = Wq[(size_t)(k + 2) * 256 + tx];
        float wq3 = Wq[(size_t)(k + 3) * 256 + tx];
        float wk0 = Wk[(size_t)k * 256 + tx];
        float wk1 = Wk[(size_t)(k + 1) * 256 + tx];
        float wk2 = Wk[(size_t)(k + 2) * 256 + tx];
        float wk3 = Wk[(size_t)(k + 3) * 256 + tx];
        float wv0 = Wv[(size_t)k * 256 + tx];
        float wv1 = Wv[(size_t)(k + 1) * 256 + tx];
        float wv2 = Wv[(size_t)(k + 2) * 256 + tx];
        float wv3 = Wv[(size_t)(k + 3) * 256 + tx];
        float ws0 = 0.f, ws1 = 0.f, ws2 = 0.f, ws3 = 0.f;
        if (do_s) {
            ws0 = Ws[(size_t)k * 64 + tx];
            ws1 = Ws[(size_t)(k + 1) * 64 + tx];
            ws2 = Ws[(size_t)(k + 2) * 64 + tx];
            ws3 = Ws[(size_t)(k + 3) * 64 + tx];
        }
#pragma unroll
        for (int r = 0; r < 16; ++r) {
            const float4 hv = *(const float4*)&ht[r][k];
            accq[r] += hv.x * wq0 + hv.y * wq1 + hv.z * wq2 + hv.w * wq3;
            acck[r] += hv.x * wk0 + hv.y * wk1 + hv.z * wk2 + hv.w * wk3;
            accv[r] += hv.x * wv0 + hv.y * wv1 + hv.z * wv2 + hv.w * wv3;
        }
        if (do_s) {
#pragma unroll
            for (int r = 0; r < 16; ++r) {
                const float4 hv = *(const float4*)&ht[r][k];
                accs[r] += hv.x * ws0 + hv.y * ws1 + hv.z * ws2 + hv.w * ws3;
            }
        }
    }

    float biasq = bq[tx], biask = bk[tx], biasv = bv[tx];
    int hh = tx >> 6, c = tx & 63;
    int posk = (hh * 16 + (c >> 2)) * 8 + (c & 3);
    int posv = posk + 4;
#pragma unroll
    for (int r = 0; r < 16; ++r) {
        size_t row = row0 + r;
        qs[row * QSS + tx] = accq[r] + biasq;
        kvpack[row * 512 + posk] = f2bf(acck[r] + biask);
        kvpack[row * 512 + posv] = f2bf(accv[r] + biasv);
    }
    if (do_s) {
        float biass = bs[tx];
#pragma unroll
        for (int r = 0; r < 16; ++r)
            qs[(size_t)(row0 + r) * QSS + 256 + tx] = accs[r] + biass;
    }
}

// ---------------- per-node edge attention (one wave per node) ----------------
// lane = hh*16 + c16; lane's 16B kvpack load holds its k4 (bf16) and v4 (bf16).

__global__ __launch_bounds__(256) void edge_kernel(const float* __restrict__ qs,
                                                   const ushort8* __restrict__ kvp,
                                                   const int* __restrict__ offs,
                                                   const int* __restrict__ csr,
                                                   float* __restrict__ hout) {
    int wave = threadIdx.x >> 6;
    int lane = threadIdx.x & 63;
    int node = blockIdx.x * 4 + wave;
    if (node >= N_NODES) return;
    int hh = lane >> 4;
    int cb = (lane & 15) * 4;

    const float* nb = qs + (size_t)node * QSS;
    float4 q = *(const float4*)(nb + hh * 64 + cb);

    float m = -INFINITY, l = 0.f;
    float4 acc = make_float4(0.f, 0.f, 0.f, 0.f);

    int e0 = offs[node], e1 = offs[node + 1];
    int cnt = e1 - e0;

    ushort8 cur = (ushort8)(0);
    ushort8 nxt = (ushort8)(0);
    if (cnt > 0) cur = kvp[(size_t)csr[e0] * 64 + lane];
    if (cnt > 1) nxt = kvp[(size_t)csr[e0 + 1] * 64 + lane];

    for (int i = 0; i < cnt; ++i) {
        ushort8 u = cur;
        cur = nxt;
        if (i + 2 < cnt) nxt = kvp[(size_t)csr[e0 + i + 2] * 64 + lane];

        float p = q.x * bf2f(u[0]) + q.y * bf2f(u[1]) + q.z * bf2f(u[2]) + q.w * bf2f(u[3]);
        p += __shfl_xor(p, 1);
        p += __shfl_xor(p, 2);
        p += __shfl_xor(p, 4);
        p += __shfl_xor(p, 8);
        float alpha = p * 0.125f;   // 1/sqrt(64)
        float nm = fmaxf(m, alpha);
        float sc = __expf(m - nm);
        float pe = __expf(alpha - nm);
        l = l * sc + pe;
        acc.x = acc.x * sc + pe * bf2f(u[4]);
        acc.y = acc.y * sc + pe * bf2f(u[5]);
        acc.z = acc.z * sc + pe * bf2f(u[6]);
        acc.w = acc.w * sc + pe * bf2f(u[7]);
        m = nm;
    }

    float inv = (l > 0.f) ? (1.f / l) : 0.f;
    float4 r;
    r.x = acc.x * inv;
    r.y = acc.y * inv;
    r.z = acc.z * inv;
    r.w = acc.w * inv;
    r.x += __shfl_xor(r.x, 16); r.x += __shfl_xor(r.x, 32);
    r.y += __shfl_xor(r.y, 16); r.y += __shfl_xor(r.y, 32);
    r.z += __shfl_xor(r.z, 16); r.z += __shfl_xor(r.z, 32);
    r.w += __shfl_xor(r.w, 16); r.w += __shfl_xor(r.w, 32);

    if (hh == 0) {
        float4 s = *(const float4*)(nb + 256 + cb);
        float4 o;
        o.x = fmaxf(r.x * 0.25f + s.x, 0.f);
        o.y = fmaxf(r.y * 0.25f + s.y, 0.f);
        o.z = fmaxf(r.z * 0.25f + s.z, 0.f);
        o.w = fmaxf(r.w * 0.25f + s.w, 0.f);
        *(float4*)(hout + (size_t)node * HID + cb) = o;
    }
}

// ---------------- global add pool ----------------

__global__ __launch_bounds__(256) void pool_kernel(const float* __restrict__ h,
                                                   const int* __restrict__ batch,
                                                   float* __restrict__ out) {
    int g = blockIdx.x;
    int lo = 0, hi = N_NODES;
    while (lo < hi) { int mid = (lo + hi) >> 1; if (batch[mid] < g) lo = mid + 1; else hi = mid; }
    int start = lo;
    hi = N_NODES;
    while (lo < hi) { int mid = (lo + hi) >> 1; if (batch[mid] < g + 1) lo = mid + 1; else hi = mid; }
    int end = lo;
    int c = threadIdx.x & 63;
    int sub = threadIdx.x >> 6;
    float acc = 0.f;
    for (int i = start + sub; i < end; i += 4) acc += h[(size_t)i * HID + c];
    __shared__ float lds[4][64];
    lds[sub][c] = acc;
    __syncthreads();
    if (sub == 0) out[g * HID + c] = lds[0][c] + lds[1][c] + lds[2][c] + lds[3][c];
}

// ---------------- launch ----------------

extern "C" void kernel_launch(void* const* d_in, const int* in_sizes, int n_in,
                              void* d_out, int out_size, void* d_ws, size_t ws_size,
                              hipStream_t stream) {
    const float* x    = (const float*)d_in[0];
    const int*   edge = (const int*)d_in[1];
    const int*   batch= (const int*)d_in[2];
    const float* linW = (const float*)d_in[3];
    const float* linb = (const float*)d_in[4];
    const float* Wq   = (const float*)d_in[5];
    const float* bq   = (const float*)d_in[6];
    const float* Wk   = (const float*)d_in[7];
    const float* bk   = (const float*)d_in[8];
    const float* Wv   = (const float*)d_in[9];
    const float* bv   = (const float*)d_in[10];
    const float* Ws   = (const float*)d_in[11];
    const float* bs   = (const float*)d_in[12];
    float* out = (float*)d_out;

    const int* src = edge;
    const int* dst = edge + N_EDGES;

    float* h0  = (float*)d_ws;                                   // N*64
    float* h1  = h0 + (size_t)N_NODES * HID;                     // N*64
    float* qs  = h1 + (size_t)N_NODES * HID;                     // N*320
    ushort* kvpack = (ushort*)(qs + (size_t)N_NODES * QSS);      // N*512 ushort
    int* counts = (int*)(kvpack + (size_t)N_NODES * 512);
    int* offs   = counts + N_NODES;
    int* cursor = offs + N_NODES + 1;
    int* csr    = cursor + N_NODES;
    int* bsum   = csr + N_EDGES;
    int* bexcl  = bsum + 128;

    const int NB = (N_NODES + 255) / 256;   // 79

    // CSR build (dst is fixed across layers)
    hipMemsetAsync(counts, 0, N_NODES * sizeof(int), stream);
    hist_kernel<<<(N_EDGES + 255) / 256, 256, 0, stream>>>(dst, counts, N_EDGES);
    blocksum_kernel<<<NB, 256, 0, stream>>>(counts, bsum, N_NODES);
    scanb_kernel<<<1, 128, 0, stream>>>(bsum, bexcl, NB);
    expand_kernel<<<NB, 256, 0, stream>>>(counts, bexcl, offs, cursor, N_NODES);
    scatter_kernel<<<(N_EDGES + 255) / 256, 256, 0, stream>>>(src, dst, cursor, csr, N_EDGES);

    // input linear
    lin_kernel<<<N_NODES / 32, 256, 0, stream>>>(x, linW, linb, h0);

    float* hc = h0;
    float* hn = h1;
    for (int l = 0; l < LAYERS; ++l) {
        proj_kernel<<<N_NODES / 16, 256, 0, stream>>>(hc,
            Wq + (size_t)l * HID * 256, bq + (size_t)l * 256,
            Wk + (size_t)l * HID * 256, bk + (size_t)l * 256,
            Wv + (size_t)l * HID * 256, bv + (size_t)l * 256,
            Ws + (size_t)l * HID * 64,  bs + (size_t)l * 64,
            qs, kvpack);
        edge_kernel<<<N_NODES / 4, 256, 0, stream>>>(qs, (const ushort8*)kvpack, offs, csr, hn);
        float* t = hc; hc = hn; hn = t;
    }

    pool_kernel<<<GRAPHS, 256, 0, stream>>>(hc, batch, out);
}

// Round 5
// 404.322 us; speedup vs baseline: 1.6305x; 1.1028x over previous
//
#include <hip/hip_runtime.h>
#include <math.h>

#define N_NODES 20000
#define N_EDGES 320000
#define DIM_IN 128
#define HID 64
#define HEADS 4
#define LAYERS 3
#define GRAPHS 128
#define QSS 320    // stored f32 cols: 256 q | 64 s

typedef unsigned short ushort;
typedef ushort ushort8 __attribute__((ext_vector_type(8)));
typedef short short8 __attribute__((ext_vector_type(8)));
typedef float f32x4 __attribute__((ext_vector_type(4)));

__device__ __forceinline__ float bf2f(ushort u) {
    return __uint_as_float(((unsigned int)u) << 16);
}
__device__ __forceinline__ ushort f2bf(float f) {
    unsigned int b = __float_as_uint(f);
    return (ushort)((b + 0x7FFFu + ((b >> 16) & 1u)) >> 16);
}

// ---------------- CSR build ----------------

__global__ void hist_kernel(const int* __restrict__ dst, int* __restrict__ counts, int n) {
    int e = blockIdx.x * 256 + threadIdx.x;
    if (e < n) atomicAdd(&counts[dst[e]], 1);
}

__global__ __launch_bounds__(256) void blocksum_kernel(const int* __restrict__ counts,
                                                       int* __restrict__ bsum, int n) {
    int i = blockIdx.x * 256 + threadIdx.x;
    int v = (i < n) ? counts[i] : 0;
    int lane = threadIdx.x & 63, wave = threadIdx.x >> 6;
#pragma unroll
    for (int off = 32; off >= 1; off >>= 1) v += __shfl_xor(v, off);
    __shared__ int ws[4];
    if (lane == 0) ws[wave] = v;
    __syncthreads();
    if (threadIdx.x == 0) bsum[blockIdx.x] = ws[0] + ws[1] + ws[2] + ws[3];
}

__global__ __launch_bounds__(128) void scanb_kernel(const int* __restrict__ bsum,
                                                    int* __restrict__ bexcl, int nb) {
    int tid = threadIdx.x;
    int v = (tid < nb) ? bsum[tid] : 0;
    int lane = tid & 63, wave = tid >> 6;
    int s = v;
#pragma unroll
    for (int off = 1; off < 64; off <<= 1) {
        int t = __shfl_up(s, off);
        if (lane >= off) s += t;
    }
    __shared__ int w0sum;
    if (tid == 63) w0sum = s;
    __syncthreads();
    int excl = s - v + (wave ? w0sum : 0);
    if (tid < nb) bexcl[tid] = excl;
}

__global__ __launch_bounds__(256) void expand_kernel(const int* __restrict__ counts,
                                                     const int* __restrict__ bexcl,
                                                     int* __restrict__ offs,
                                                     int* __restrict__ cursor, int n) {
    int i = blockIdx.x * 256 + threadIdx.x;
    int v = (i < n) ? counts[i] : 0;
    int lane = threadIdx.x & 63, wave = threadIdx.x >> 6;
    int s = v;
#pragma unroll
    for (int off = 1; off < 64; off <<= 1) {
        int t = __shfl_up(s, off);
        if (lane >= off) s += t;
    }
    __shared__ int wsum[4];
    if (lane == 63) wsum[wave] = s;
    __syncthreads();
    int add = bexcl[blockIdx.x];
    for (int w = 0; w < wave; ++w) add += wsum[w];
    int excl = add + s - v;
    if (i < n) { offs[i] = excl; cursor[i] = excl; }
    if (i == 0) offs[n] = N_EDGES;
}

__global__ void scatter_kernel(const int* __restrict__ src, const int* __restrict__ dst,
                               int* __restrict__ cursor, int* __restrict__ csr, int n) {
    int e = blockIdx.x * 256 + threadIdx.x;
    if (e < n) {
        int d = dst[e];
        int pos = atomicAdd(&cursor[d], 1);
        csr[pos] = src[e];
    }
}

// ---------------- input linear: h0 = x @ linW + linb ----------------

__global__ __launch_bounds__(256) void lin_kernel(const float* __restrict__ x,
                                                  const float* __restrict__ W,
                                                  const float* __restrict__ b,
                                                  float* __restrict__ h0) {
    __shared__ float xt[32][DIM_IN];
    int tx = threadIdx.x;
    int row0 = blockIdx.x * 32;
    for (int idx = tx; idx < 32 * DIM_IN; idx += 256) {
        int r = idx / DIM_IN, c = idx % DIM_IN;
        xt[r][c] = x[(size_t)(row0 + r) * DIM_IN + c];
    }
    __syncthreads();
    int col = tx & 63;
    int sub = tx >> 6;
    float acc[8];
#pragma unroll
    for (int r = 0; r < 8; ++r) acc[r] = 0.f;
    for (int k = 0; k < DIM_IN; k += 4) {
        float w0 = W[k * HID + col];
        float w1 = W[(k + 1) * HID + col];
        float w2 = W[(k + 2) * HID + col];
        float w3 = W[(k + 3) * HID + col];
#pragma unroll
        for (int r = 0; r < 8; ++r) {
            const float4 hv = *(const float4*)&xt[r * 4 + sub][k];
            acc[r] += hv.x * w0 + hv.y * w1 + hv.z * w2 + hv.w * w3;
        }
    }
    float bias = b[col];
#pragma unroll
    for (int r = 0; r < 8; ++r) {
        int row = row0 + r * 4 + sub;
        h0[(size_t)row * HID + col] = acc[r] + bias;
    }
}

// ---------------- per-layer weight convert ----------------
// Wt[832][64] bf16:  Wt[j][k] = W*(k, j)   (j: 0-255 q | 256-511 k | 512-767 v | 768-831 s)
// bias_cat[832] f32.

__global__ __launch_bounds__(256) void wcvt_kernel(const float* __restrict__ Wq, const float* __restrict__ bq,
                                                   const float* __restrict__ Wk, const float* __restrict__ bk,
                                                   const float* __restrict__ Wv, const float* __restrict__ bv,
                                                   const float* __restrict__ Ws, const float* __restrict__ bs,
                                                   ushort* __restrict__ Wt, float* __restrict__ bias_cat) {
    int idx = blockIdx.x * 256 + threadIdx.x;
    if (idx < 832 * 64) {
        int j = idx >> 6, k = idx & 63;
        float w;
        if (j < 256)      w = Wq[(size_t)k * 256 + j];
        else if (j < 512) w = Wk[(size_t)k * 256 + (j - 256)];
        else if (j < 768) w = Wv[(size_t)k * 256 + (j - 512)];
        else              w = Ws[(size_t)k * 64 + (j - 768)];
        Wt[idx] = f2bf(w);
    }
    if (idx < 832) {
        float b;
        if (idx < 256)      b = bq[idx];
        else if (idx < 512) b = bk[idx - 256];
        else if (idx < 768) b = bv[idx - 512];
        else                b = bs[idx - 768];
        bias_cat[idx] = b;
    }
}

// ---------------- per-layer projection via MFMA bf16 ----------------
// Block: 512 threads = 8 waves, covers 32 rows.
// Wave w: rows r0 = blk*32 + (w&1)*16, cols [c0, c0+208), c0 = (w>>1)*208.
// 13 tiles of 16x16 per wave; K=64 as two 16x16x32 MFMAs.
// A-frag: row = lane&15, k = (lane>>4)*8 + [0..8)  (f32 h loaded + packed to bf16)
// B-frag: col = lane&15, k likewise, from Wt[col][k] (16B contiguous)
// C/D:    col = lane&15, row = (lane>>4)*4 + reg

__global__ __launch_bounds__(512) void proj_kernel(const float* __restrict__ h,
                                                   const ushort* __restrict__ Wt,
                                                   const float* __restrict__ bias_cat,
                                                   float* __restrict__ qs,
                                                   ushort* __restrict__ kvpack) {
    int tid = threadIdx.x;
    int w = tid >> 6, l = tid & 63;
    int r0 = blockIdx.x * 32 + (w & 1) * 16;
    int c0 = (w >> 1) * 208;
    int row = r0 + (l & 15);
    int koff = (l >> 4) * 8;

    short8 a[2];
#pragma unroll
    for (int m = 0; m < 2; ++m) {
        const float* hp = h + (size_t)row * HID + m * 32 + koff;
        float4 f0 = *(const float4*)hp;
        float4 f1 = *(const float4*)(hp + 4);
        ushort8 u;
        u[0] = f2bf(f0.x); u[1] = f2bf(f0.y); u[2] = f2bf(f0.z); u[3] = f2bf(f0.w);
        u[4] = f2bf(f1.x); u[5] = f2bf(f1.y); u[6] = f2bf(f1.z); u[7] = f2bf(f1.w);
        a[m] = __builtin_bit_cast(short8, u);
    }

    f32x4 acc[13];
#pragma unroll
    for (int t = 0; t < 13; ++t) acc[t] = (f32x4){0.f, 0.f, 0.f, 0.f};

    const ushort* wb = Wt + ((size_t)(c0 + (l & 15))) * HID + koff;
#pragma unroll
    for (int t = 0; t < 13; ++t) {
        short8 b0 = *(const short8*)(wb + (size_t)t * 16 * HID);
        short8 b1 = *(const short8*)(wb + (size_t)t * 16 * HID + 32);
        acc[t] = __builtin_amdgcn_mfma_f32_16x16x32_bf16(a[0], b0, acc[t], 0, 0, 0);
        acc[t] = __builtin_amdgcn_mfma_f32_16x16x32_bf16(a[1], b1, acc[t], 0, 0, 0);
    }

    int colbase = c0 + (l & 15);
    int rbase = r0 + ((l >> 4) << 2);
#pragma unroll
    for (int t = 0; t < 13; ++t) {
        int j = colbase + t * 16;
        float bias = bias_cat[j];
        if (j < 256) {
#pragma unroll
            for (int i = 0; i < 4; ++i)
                qs[(size_t)(rbase + i) * QSS + j] = acc[t][i] + bias;
        } else if (j < 768) {
            int ck = j - 256;
            int isv = ck >> 8;
            int ch = ck & 255;
            int hh2 = ch >> 6, c = ch & 63;
            int pos = (hh2 * 16 + (c >> 2)) * 8 + isv * 4 + (c & 3);
#pragma unroll
            for (int i = 0; i < 4; ++i)
                kvpack[(size_t)(rbase + i) * 512 + pos] = f2bf(acc[t][i] + bias);
        } else {
#pragma unroll
            for (int i = 0; i < 4; ++i)
                qs[(size_t)(rbase + i) * QSS + 256 + (j - 768)] = acc[t][i] + bias;
        }
    }
}

// ---------------- per-node edge attention (one wave per node) ----------------
// lane = hh*16 + c16; lane's 16B kvpack load holds its k4 (bf16) and v4 (bf16).

__global__ __launch_bounds__(256) void edge_kernel(const float* __restrict__ qs,
                                                   const ushort8* __restrict__ kvp,
                                                   const int* __restrict__ offs,
                                                   const int* __restrict__ csr,
                                                   float* __restrict__ hout) {
    int wave = threadIdx.x >> 6;
    int lane = threadIdx.x & 63;
    int node = blockIdx.x * 4 + wave;
    if (node >= N_NODES) return;
    int hh = lane >> 4;
    int cb = (lane & 15) * 4;

    const float* nb = qs + (size_t)node * QSS;
    float4 q = *(const float4*)(nb + hh * 64 + cb);

    float m = -INFINITY, l = 0.f;
    float4 acc = make_float4(0.f, 0.f, 0.f, 0.f);

    int e0 = offs[node], e1 = offs[node + 1];
    int cnt = e1 - e0;

    ushort8 cur = (ushort8)(0);
    ushort8 nxt = (ushort8)(0);
    if (cnt > 0) cur = kvp[(size_t)csr[e0] * 64 + lane];
    if (cnt > 1) nxt = kvp[(size_t)csr[e0 + 1] * 64 + lane];

    for (int i = 0; i < cnt; ++i) {
        ushort8 u = cur;
        cur = nxt;
        if (i + 2 < cnt) nxt = kvp[(size_t)csr[e0 + i + 2] * 64 + lane];

        float p = q.x * bf2f(u[0]) + q.y * bf2f(u[1]) + q.z * bf2f(u[2]) + q.w * bf2f(u[3]);
        p += __shfl_xor(p, 1);
        p += __shfl_xor(p, 2);
        p += __shfl_xor(p, 4);
        p += __shfl_xor(p, 8);
        float alpha = p * 0.125f;   // 1/sqrt(64)
        float nm = fmaxf(m, alpha);
        float sc = __expf(m - nm);
        float pe = __expf(alpha - nm);
        l = l * sc + pe;
        acc.x = acc.x * sc + pe * bf2f(u[4]);
        acc.y = acc.y * sc + pe * bf2f(u[5]);
        acc.z = acc.z * sc + pe * bf2f(u[6]);
        acc.w = acc.w * sc + pe * bf2f(u[7]);
        m = nm;
    }

    float inv = (l > 0.f) ? (1.f / l) : 0.f;
    float4 r;
    r.x = acc.x * inv;
    r.y = acc.y * inv;
    r.z = acc.z * inv;
    r.w = acc.w * inv;
    r.x += __shfl_xor(r.x, 16); r.x += __shfl_xor(r.x, 32);
    r.y += __shfl_xor(r.y, 16); r.y += __shfl_xor(r.y, 32);
    r.z += __shfl_xor(r.z, 16); r.z += __shfl_xor(r.z, 32);
    r.w += __shfl_xor(r.w, 16); r.w += __shfl_xor(r.w, 32);

    if (hh == 0) {
        float4 s = *(const float4*)(nb + 256 + cb);
        float4 o;
        o.x = fmaxf(r.x * 0.25f + s.x, 0.f);
        o.y = fmaxf(r.y * 0.25f + s.y, 0.f);
        o.z = fmaxf(r.z * 0.25f + s.z, 0.f);
        o.w = fmaxf(r.w * 0.25f + s.w, 0.f);
        *(float4*)(hout + (size_t)node * HID + cb) = o;
    }
}

// ---------------- global add pool ----------------

__global__ __launch_bounds__(256) void pool_kernel(const float* __restrict__ h,
                                                   const int* __restrict__ batch,
                                                   float* __restrict__ out) {
    int g = blockIdx.x;
    int lo = 0, hi = N_NODES;
    while (lo < hi) { int mid = (lo + hi) >> 1; if (batch[mid] < g) lo = mid + 1; else hi = mid; }
    int start = lo;
    hi = N_NODES;
    while (lo < hi) { int mid = (lo + hi) >> 1; if (batch[mid] < g + 1) lo = mid + 1; else hi = mid; }
    int end = lo;
    int c = threadIdx.x & 63;
    int sub = threadIdx.x >> 6;
    float acc = 0.f;
    for (int i = start + sub; i < end; i += 4) acc += h[(size_t)i * HID + c];
    __shared__ float lds[4][64];
    lds[sub][c] = acc;
    __syncthreads();
    if (sub == 0) out[g * HID + c] = lds[0][c] + lds[1][c] + lds[2][c] + lds[3][c];
}

// ---------------- launch ----------------

extern "C" void kernel_launch(void* const* d_in, const int* in_sizes, int n_in,
                              void* d_out, int out_size, void* d_ws, size_t ws_size,
                              hipStream_t stream) {
    const float* x    = (const float*)d_in[0];
    const int*   edge = (const int*)d_in[1];
    const int*   batch= (const int*)d_in[2];
    const float* linW = (const float*)d_in[3];
    const float* linb = (const float*)d_in[4];
    const float* Wq   = (const float*)d_in[5];
    const float* bq   = (const float*)d_in[6];
    const float* Wk   = (const float*)d_in[7];
    const float* bk   = (const float*)d_in[8];
    const float* Wv   = (const float*)d_in[9];
    const float* bv   = (const float*)d_in[10];
    const float* Ws   = (const float*)d_in[11];
    const float* bs   = (const float*)d_in[12];
    float* out = (float*)d_out;

    const int* src = edge;
    const int* dst = edge + N_EDGES;

    float* h0  = (float*)d_ws;                                   // N*64
    float* h1  = h0 + (size_t)N_NODES * HID;                     // N*64
    float* qs  = h1 + (size_t)N_NODES * HID;                     // N*320
    ushort* kvpack = (ushort*)(qs + (size_t)N_NODES * QSS);      // N*512 ushort
    int* counts = (int*)(kvpack + (size_t)N_NODES * 512);
    int* offs   = counts + N_NODES;
    int* cursor = offs + N_NODES + 1;
    int* csr    = cursor + N_NODES;
    int* bsum   = csr + N_EDGES;
    int* bexcl  = bsum + 128;
    ushort* Wt  = (ushort*)(bexcl + 128);                        // 832*64 ushort
    float* bias_cat = (float*)(Wt + 832 * 64);                   // 832 f32

    const int NB = (N_NODES + 255) / 256;   // 79

    // CSR build (dst is fixed across layers)
    hipMemsetAsync(counts, 0, N_NODES * sizeof(int), stream);
    hist_kernel<<<(N_EDGES + 255) / 256, 256, 0, stream>>>(dst, counts, N_EDGES);
    blocksum_kernel<<<NB, 256, 0, stream>>>(counts, bsum, N_NODES);
    scanb_kernel<<<1, 128, 0, stream>>>(bsum, bexcl, NB);
    expand_kernel<<<NB, 256, 0, stream>>>(counts, bexcl, offs, cursor, N_NODES);
    scatter_kernel<<<(N_EDGES + 255) / 256, 256, 0, stream>>>(src, dst, cursor, csr, N_EDGES);

    // input linear
    lin_kernel<<<N_NODES / 32, 256, 0, stream>>>(x, linW, linb, h0);

    float* hc = h0;
    float* hn = h1;
    for (int l = 0; l < LAYERS; ++l) {
        wcvt_kernel<<<(832 * 64 + 255) / 256, 256, 0, stream>>>(
            Wq + (size_t)l * HID * 256, bq + (size_t)l * 256,
            Wk + (size_t)l * HID * 256, bk + (size_t)l * 256,
            Wv + (size_t)l * HID * 256, bv + (size_t)l * 256,
            Ws + (size_t)l * HID * 64,  bs + (size_t)l * 64,
            Wt, bias_cat);
        proj_kernel<<<N_NODES / 32, 512, 0, stream>>>(hc, Wt, bias_cat, qs, kvpack);
        edge_kernel<<<N_NODES / 4, 256, 0, stream>>>(qs, (const ushort8*)kvpack, offs, csr, hn);
        float* t = hc; hc = hn; hn = t;
    }

    pool_kernel<<<GRAPHS, 256, 0, stream>>>(hc, batch, out);
}

// Round 6
// 396.490 us; speedup vs baseline: 1.6627x; 1.0198x over previous
//
#include <hip/hip_runtime.h>
#include <math.h>

#define N_NODES 20000
#define N_EDGES 320000
#define DIM_IN 128
#define HID 64
#define HEADS 4
#define LAYERS 3
#define GRAPHS 128
#define QSS 320    // stored f32 cols: 256 q | 64 s

typedef unsigned short ushort;
typedef ushort ushort8 __attribute__((ext_vector_type(8)));
typedef short short8 __attribute__((ext_vector_type(8)));
typedef float f32x4 __attribute__((ext_vector_type(4)));

__device__ __forceinline__ float bf2f(ushort u) {
    return __uint_as_float(((unsigned int)u) << 16);
}
__device__ __forceinline__ ushort f2bf(float f) {
    unsigned int b = __float_as_uint(f);
    return (ushort)((b + 0x7FFFu + ((b >> 16) & 1u)) >> 16);
}

// ---------------- CSR build ----------------

__global__ void hist_kernel(const int* __restrict__ dst, int* __restrict__ counts, int n) {
    int e = blockIdx.x * 256 + threadIdx.x;
    if (e < n) atomicAdd(&counts[dst[e]], 1);
}

__global__ __launch_bounds__(256) void blocksum_kernel(const int* __restrict__ counts,
                                                       int* __restrict__ bsum, int n) {
    int i = blockIdx.x * 256 + threadIdx.x;
    int v = (i < n) ? counts[i] : 0;
    int lane = threadIdx.x & 63, wave = threadIdx.x >> 6;
#pragma unroll
    for (int off = 32; off >= 1; off >>= 1) v += __shfl_xor(v, off);
    __shared__ int ws[4];
    if (lane == 0) ws[wave] = v;
    __syncthreads();
    if (threadIdx.x == 0) bsum[blockIdx.x] = ws[0] + ws[1] + ws[2] + ws[3];
}

__global__ __launch_bounds__(128) void scanb_kernel(const int* __restrict__ bsum,
                                                    int* __restrict__ bexcl, int nb) {
    int tid = threadIdx.x;
    int v = (tid < nb) ? bsum[tid] : 0;
    int lane = tid & 63, wave = tid >> 6;
    int s = v;
#pragma unroll
    for (int off = 1; off < 64; off <<= 1) {
        int t = __shfl_up(s, off);
        if (lane >= off) s += t;
    }
    __shared__ int w0sum;
    if (tid == 63) w0sum = s;
    __syncthreads();
    int excl = s - v + (wave ? w0sum : 0);
    if (tid < nb) bexcl[tid] = excl;
}

__global__ __launch_bounds__(256) void expand_kernel(const int* __restrict__ counts,
                                                     const int* __restrict__ bexcl,
                                                     int* __restrict__ offs,
                                                     int* __restrict__ cursor, int n) {
    int i = blockIdx.x * 256 + threadIdx.x;
    int v = (i < n) ? counts[i] : 0;
    int lane = threadIdx.x & 63, wave = threadIdx.x >> 6;
    int s = v;
#pragma unroll
    for (int off = 1; off < 64; off <<= 1) {
        int t = __shfl_up(s, off);
        if (lane >= off) s += t;
    }
    __shared__ int wsum[4];
    if (lane == 63) wsum[wave] = s;
    __syncthreads();
    int add = bexcl[blockIdx.x];
    for (int w = 0; w < wave; ++w) add += wsum[w];
    int excl = add + s - v;
    if (i < n) { offs[i] = excl; cursor[i] = excl; }
    if (i == 0) offs[n] = N_EDGES;
}

__global__ void scatter_kernel(const int* __restrict__ src, const int* __restrict__ dst,
                               int* __restrict__ cursor, int* __restrict__ csr, int n) {
    int e = blockIdx.x * 256 + threadIdx.x;
    if (e < n) {
        int d = dst[e];
        int pos = atomicAdd(&cursor[d], 1);
        csr[pos] = src[e];
    }
}

// ---------------- one-shot weight convert (all layers + input linear) ----------------
// Wt3[l][832][64] bf16, col j of layer l:
//   j <256   : q col j
//   256..767 : permuted k/v col — pout=j-256; isv=(pout>>2)&1; low2=pout&3; g=pout>>3;
//              srccol=(g>>4)*64+(g&15)*4+low2; from Wk (isv=0) or Wv (isv=1)
//   >=768    : s col j-768
// bias3[l][832] matches. Wlt[64][128] bf16 from linW.

__global__ __launch_bounds__(256) void wcvt_all_kernel(
        const float* __restrict__ Wq, const float* __restrict__ bq,
        const float* __restrict__ Wk, const float* __restrict__ bk,
        const float* __restrict__ Wv, const float* __restrict__ bv,
        const float* __restrict__ Ws, const float* __restrict__ bs,
        const float* __restrict__ linW,
        ushort* __restrict__ Wt3, float* __restrict__ bias3,
        ushort* __restrict__ Wlt) {
    const int PER = 832 * 64;
    int idx = blockIdx.x * 256 + threadIdx.x;
    if (idx < 3 * PER) {
        int l = idx / PER;
        int r = idx - l * PER;
        int j = r >> 6, k = r & 63;
        const float* Wq_l = Wq + (size_t)l * HID * 256;
        const float* Wk_l = Wk + (size_t)l * HID * 256;
        const float* Wv_l = Wv + (size_t)l * HID * 256;
        const float* Ws_l = Ws + (size_t)l * HID * 64;
        float w;
        if (j < 256) {
            w = Wq_l[(size_t)k * 256 + j];
        } else if (j < 768) {
            int pout = j - 256;
            int isv = (pout >> 2) & 1;
            int low2 = pout & 3;
            int g = pout >> 3;
            int srccol = (g >> 4) * 64 + (g & 15) * 4 + low2;
            w = isv ? Wv_l[(size_t)k * 256 + srccol] : Wk_l[(size_t)k * 256 + srccol];
        } else {
            w = Ws_l[(size_t)k * 64 + (j - 768)];
        }
        Wt3[idx] = f2bf(w);
    } else {
        int idx2 = idx - 3 * PER;
        if (idx2 < 64 * DIM_IN) {
            int col = idx2 >> 7, k = idx2 & 127;
            Wlt[idx2] = f2bf(linW[(size_t)k * HID + col]);
        }
    }
    if (idx < 3 * 832) {
        int l = idx / 832, j = idx - l * 832;
        float b;
        if (j < 256) {
            b = bq[l * 256 + j];
        } else if (j < 768) {
            int pout = j - 256;
            int isv = (pout >> 2) & 1;
            int low2 = pout & 3;
            int g = pout >> 3;
            int srccol = (g >> 4) * 64 + (g & 15) * 4 + low2;
            b = isv ? bv[l * 256 + srccol] : bk[l * 256 + srccol];
        } else {
            b = bs[l * 64 + (j - 768)];
        }
        bias3[idx] = b;
    }
}

// ---------------- input linear via MFMA: h0 = x @ linW + linb ----------------
// Block: 4 waves, 64 rows. Wave w: rows blk*64 + w*16, cols 0..63 (4 tiles), K=128.

__global__ __launch_bounds__(256) void lin_kernel(const float* __restrict__ x,
                                                  const ushort* __restrict__ Wlt,
                                                  const float* __restrict__ lb,
                                                  float* __restrict__ h0) {
    int tid = threadIdx.x;
    int w = tid >> 6, l = tid & 63;
    int r0 = blockIdx.x * 64 + w * 16;
    int row = r0 + (l & 15);
    int rowc = (row < N_NODES) ? row : (N_NODES - 1);

    short8 a[4];
#pragma unroll
    for (int kc = 0; kc < 4; ++kc) {
        const float* xp = x + (size_t)rowc * DIM_IN + kc * 32 + (l >> 4) * 8;
        float4 f0 = *(const float4*)xp;
        float4 f1 = *(const float4*)(xp + 4);
        ushort8 u;
        u[0] = f2bf(f0.x); u[1] = f2bf(f0.y); u[2] = f2bf(f0.z); u[3] = f2bf(f0.w);
        u[4] = f2bf(f1.x); u[5] = f2bf(f1.y); u[6] = f2bf(f1.z); u[7] = f2bf(f1.w);
        a[kc] = __builtin_bit_cast(short8, u);
    }

    f32x4 acc[4];
#pragma unroll
    for (int t = 0; t < 4; ++t) acc[t] = (f32x4){0.f, 0.f, 0.f, 0.f};

    const ushort* wb = Wlt + (size_t)(l & 15) * DIM_IN + (l >> 4) * 8;
#pragma unroll
    for (int t = 0; t < 4; ++t) {
#pragma unroll
        for (int kc = 0; kc < 4; ++kc) {
            short8 b = *(const short8*)(wb + (size_t)t * 16 * DIM_IN + kc * 32);
            acc[t] = __builtin_amdgcn_mfma_f32_16x16x32_bf16(a[kc], b, acc[t], 0, 0, 0);
        }
    }

    int rbase = r0 + ((l >> 4) << 2);
#pragma unroll
    for (int t = 0; t < 4; ++t) {
        int col = t * 16 + (l & 15);
        float bias = lb[col];
#pragma unroll
        for (int i = 0; i < 4; ++i) {
            int rr = rbase + i;
            if (rr < N_NODES) h0[(size_t)rr * HID + col] = acc[t][i] + bias;
        }
    }
}

// ---------------- per-layer projection via MFMA bf16 ----------------
// Block: 512 threads = 8 waves, covers 32 rows.
// Wave w: rows r0 = blk*32 + (w&1)*16, cols [c0, c0+208), c0 = (w>>1)*208.

__global__ __launch_bounds__(512) void proj_kernel(const float* __restrict__ h,
                                                   const ushort* __restrict__ Wt,
                                                   const float* __restrict__ bias_cat,
                                                   float* __restrict__ qs,
                                                   ushort* __restrict__ kvpack) {
    int tid = threadIdx.x;
    int w = tid >> 6, l = tid & 63;
    int r0 = blockIdx.x * 32 + (w & 1) * 16;
    int c0 = (w >> 1) * 208;
    int row = r0 + (l & 15);
    int koff = (l >> 4) * 8;

    short8 a[2];
#pragma unroll
    for (int m = 0; m < 2; ++m) {
        const float* hp = h + (size_t)row * HID + m * 32 + koff;
        float4 f0 = *(const float4*)hp;
        float4 f1 = *(const float4*)(hp + 4);
        ushort8 u;
        u[0] = f2bf(f0.x); u[1] = f2bf(f0.y); u[2] = f2bf(f0.z); u[3] = f2bf(f0.w);
        u[4] = f2bf(f1.x); u[5] = f2bf(f1.y); u[6] = f2bf(f1.z); u[7] = f2bf(f1.w);
        a[m] = __builtin_bit_cast(short8, u);
    }

    f32x4 acc[13];
#pragma unroll
    for (int t = 0; t < 13; ++t) acc[t] = (f32x4){0.f, 0.f, 0.f, 0.f};

    const ushort* wb = Wt + ((size_t)(c0 + (l & 15))) * HID + koff;
#pragma unroll
    for (int t = 0; t < 13; ++t) {
        short8 b0 = *(const short8*)(wb + (size_t)t * 16 * HID);
        short8 b1 = *(const short8*)(wb + (size_t)t * 16 * HID + 32);
        acc[t] = __builtin_amdgcn_mfma_f32_16x16x32_bf16(a[0], b0, acc[t], 0, 0, 0);
        acc[t] = __builtin_amdgcn_mfma_f32_16x16x32_bf16(a[1], b1, acc[t], 0, 0, 0);
    }

    int colbase = c0 + (l & 15);
    int rbase = r0 + ((l >> 4) << 2);
#pragma unroll
    for (int t = 0; t < 13; ++t) {
        int j = colbase + t * 16;
        float bias = bias_cat[j];
        if (j < 256) {
#pragma unroll
            for (int i = 0; i < 4; ++i)
                qs[(size_t)(rbase + i) * QSS + j] = acc[t][i] + bias;
        } else if (j < 768) {
            int pout = j - 256;   // permuted layout: store position == column
#pragma unroll
            for (int i = 0; i < 4; ++i)
                kvpack[(size_t)(rbase + i) * 512 + pout] = f2bf(acc[t][i] + bias);
        } else {
#pragma unroll
            for (int i = 0; i < 4; ++i)
                qs[(size_t)(rbase + i) * QSS + 256 + (j - 768)] = acc[t][i] + bias;
        }
    }
}

// ---------------- per-node edge attention (one wave per node) ----------------
// lane = hh*16 + c16; lane's 16B kvpack load holds its k4 (bf16) and v4 (bf16).
// 8-deep batched prefetch pipeline; rescale only on new max (wave-uniform).

#define LD1(DST, EI) { int ee = (EI) < e1 ? (EI) : (e1 - 1); DST = kvp[(size_t)csr[ee] * 64 + lane]; }

#define PROC(U, EI) do { \
    float p = q.x * bf2f(U[0]) + q.y * bf2f(U[1]) + q.z * bf2f(U[2]) + q.w * bf2f(U[3]); \
    p += __shfl_xor(p, 1); \
    p += __shfl_xor(p, 2); \
    p += __shfl_xor(p, 4); \
    p += __shfl_xor(p, 8); \
    float alpha = ((EI) < e1) ? p * 0.125f : -INFINITY; \
    if (__any(alpha > m)) { \
        float nm = fmaxf(m, alpha); \
        float sc = __expf(m - nm); \
        l *= sc; acc.x *= sc; acc.y *= sc; acc.z *= sc; acc.w *= sc; \
        m = nm; \
    } \
    float pe = __expf(alpha - m); \
    l += pe; \
    acc.x += pe * bf2f(U[4]); \
    acc.y += pe * bf2f(U[5]); \
    acc.z += pe * bf2f(U[6]); \
    acc.w += pe * bf2f(U[7]); \
} while (0)

__global__ __launch_bounds__(256) void edge_kernel(const float* __restrict__ qs,
                                                   const ushort8* __restrict__ kvp,
                                                   const int* __restrict__ offs,
                                                   const int* __restrict__ csr,
                                                   float* __restrict__ hout) {
    int wave = threadIdx.x >> 6;
    int lane = threadIdx.x & 63;
    int node = blockIdx.x * 4 + wave;
    if (node >= N_NODES) return;
    int hh = lane >> 4;
    int cb = (lane & 15) * 4;

    const float* nb = qs + (size_t)node * QSS;
    float4 q = *(const float4*)(nb + hh * 64 + cb);

    float m = -INFINITY, l = 0.f;
    float4 acc = make_float4(0.f, 0.f, 0.f, 0.f);

    int e0 = offs[node], e1 = offs[node + 1];
    int cnt = e1 - e0;

    if (cnt > 0) {
        ushort8 A0, A1, A2, A3, A4, A5, A6, A7;
        LD1(A0, e0 + 0); LD1(A1, e0 + 1); LD1(A2, e0 + 2); LD1(A3, e0 + 3);
        LD1(A4, e0 + 4); LD1(A5, e0 + 5); LD1(A6, e0 + 6); LD1(A7, e0 + 7);
        for (int base = e0; base < e1; base += 8) {
            ushort8 B0, B1, B2, B3, B4, B5, B6, B7;
            bool more = (base + 8) < e1;
            if (more) {
                LD1(B0, base + 8);  LD1(B1, base + 9);  LD1(B2, base + 10); LD1(B3, base + 11);
                LD1(B4, base + 12); LD1(B5, base + 13); LD1(B6, base + 14); LD1(B7, base + 15);
            }
            PROC(A0, base + 0); PROC(A1, base + 1); PROC(A2, base + 2); PROC(A3, base + 3);
            PROC(A4, base + 4); PROC(A5, base + 5); PROC(A6, base + 6); PROC(A7, base + 7);
            if (more) {
                A0 = B0; A1 = B1; A2 = B2; A3 = B3;
                A4 = B4; A5 = B5; A6 = B6; A7 = B7;
            }
        }
    }

    float inv = (l > 0.f) ? (1.f / l) : 0.f;
    float4 r;
    r.x = acc.x * inv;
    r.y = acc.y * inv;
    r.z = acc.z * inv;
    r.w = acc.w * inv;
    r.x += __shfl_xor(r.x, 16); r.x += __shfl_xor(r.x, 32);
    r.y += __shfl_xor(r.y, 16); r.y += __shfl_xor(r.y, 32);
    r.z += __shfl_xor(r.z, 16); r.z += __shfl_xor(r.z, 32);
    r.w += __shfl_xor(r.w, 16); r.w += __shfl_xor(r.w, 32);

    if (hh == 0) {
        float4 s = *(const float4*)(nb + 256 + cb);
        float4 o;
        o.x = fmaxf(r.x * 0.25f + s.x, 0.f);
        o.y = fmaxf(r.y * 0.25f + s.y, 0.f);
        o.z = fmaxf(r.z * 0.25f + s.z, 0.f);
        o.w = fmaxf(r.w * 0.25f + s.w, 0.f);
        *(float4*)(hout + (size_t)node * HID + cb) = o;
    }
}

// ---------------- global add pool ----------------

__global__ __launch_bounds__(256) void pool_kernel(const float* __restrict__ h,
                                                   const int* __restrict__ batch,
                                                   float* __restrict__ out) {
    int g = blockIdx.x;
    int lo = 0, hi = N_NODES;
    while (lo < hi) { int mid = (lo + hi) >> 1; if (batch[mid] < g) lo = mid + 1; else hi = mid; }
    int start = lo;
    hi = N_NODES;
    while (lo < hi) { int mid = (lo + hi) >> 1; if (batch[mid] < g + 1) lo = mid + 1; else hi = mid; }
    int end = lo;
    int c = threadIdx.x & 63;
    int sub = threadIdx.x >> 6;
    float acc = 0.f;
    for (int i = start + sub; i < end; i += 4) acc += h[(size_t)i * HID + c];
    __shared__ float lds[4][64];
    lds[sub][c] = acc;
    __syncthreads();
    if (sub == 0) out[g * HID + c] = lds[0][c] + lds[1][c] + lds[2][c] + lds[3][c];
}

// ---------------- launch ----------------

extern "C" void kernel_launch(void* const* d_in, const int* in_sizes, int n_in,
                              void* d_out, int out_size, void* d_ws, size_t ws_size,
                              hipStream_t stream) {
    const float* x    = (const float*)d_in[0];
    const int*   edge = (const int*)d_in[1];
    const int*   batch= (const int*)d_in[2];
    const float* linW = (const float*)d_in[3];
    const float* linb = (const float*)d_in[4];
    const float* Wq   = (const float*)d_in[5];
    const float* bq   = (const float*)d_in[6];
    const float* Wk   = (const float*)d_in[7];
    const float* bk   = (const float*)d_in[8];
    const float* Wv   = (const float*)d_in[9];
    const float* bv   = (const float*)d_in[10];
    const float* Ws   = (const float*)d_in[11];
    const float* bs   = (const float*)d_in[12];
    float* out = (float*)d_out;

    const int* src = edge;
    const int* dst = edge + N_EDGES;

    float* h0  = (float*)d_ws;                                   // N*64
    float* h1  = h0 + (size_t)N_NODES * HID;                     // N*64
    float* qs  = h1 + (size_t)N_NODES * HID;                     // N*320
    ushort* kvpack = (ushort*)(qs + (size_t)N_NODES * QSS);      // N*512 ushort
    int* counts = (int*)(kvpack + (size_t)N_NODES * 512);
    int* offs   = counts + N_NODES;
    int* cursor = offs + N_NODES + 1;
    int* csr    = cursor + N_NODES;
    int* bsum   = csr + N_EDGES;
    int* bexcl  = bsum + 128;
    ushort* Wt3 = (ushort*)(bexcl + 128);                        // 3*832*64 ushort
    float* bias3 = (float*)(Wt3 + 3 * 832 * 64);                 // 3*832 f32
    ushort* Wlt = (ushort*)(bias3 + 3 * 832);                    // 64*128 ushort

    const int NB = (N_NODES + 255) / 256;   // 79

    // CSR build (dst is fixed across layers)
    hipMemsetAsync(counts, 0, N_NODES * sizeof(int), stream);
    hist_kernel<<<(N_EDGES + 255) / 256, 256, 0, stream>>>(dst, counts, N_EDGES);
    blocksum_kernel<<<NB, 256, 0, stream>>>(counts, bsum, N_NODES);
    scanb_kernel<<<1, 128, 0, stream>>>(bsum, bexcl, NB);
    expand_kernel<<<NB, 256, 0, stream>>>(counts, bexcl, offs, cursor, N_NODES);
    scatter_kernel<<<(N_EDGES + 255) / 256, 256, 0, stream>>>(src, dst, cursor, csr, N_EDGES);

    // one-shot weight conversion (3 layers + input linear)
    wcvt_all_kernel<<<(3 * 832 * 64 + 64 * DIM_IN + 255) / 256, 256, 0, stream>>>(
        Wq, bq, Wk, bk, Wv, bv, Ws, bs, linW, Wt3, bias3, Wlt);

    // input linear (MFMA)
    lin_kernel<<<(N_NODES + 63) / 64, 256, 0, stream>>>(x, Wlt, linb, h0);

    float* hc = h0;
    float* hn = h1;
    for (int l = 0; l < LAYERS; ++l) {
        proj_kernel<<<N_NODES / 32, 512, 0, stream>>>(hc,
            Wt3 + (size_t)l * 832 * 64, bias3 + (size_t)l * 832, qs, kvpack);
        edge_kernel<<<N_NODES / 4, 256, 0, stream>>>(qs, (const ushort8*)kvpack, offs, csr, hn);
        float* t = hc; hc = hn; hn = t;
    }

    pool_kernel<<<GRAPHS, 256, 0, stream>>>(hc, batch, out);
}